// Round 10
// baseline (89.414 us; speedup 1.0000x reference)
//
#include <hip/hip_runtime.h>

typedef unsigned short u16;
typedef __attribute__((ext_vector_type(8))) short short8;
typedef __attribute__((ext_vector_type(4))) float f32x4;

#define SEQ 3072
#define HID 1024
#define HEADS 16
#define HDIM 64
#define SEGLEN 380
#define SEGSTR 381
#define NSEG 8
#define LTOT 3047
#define VPAD 384  // padded per-segment stride in vT (16B-aligned bases)

static __device__ __forceinline__ u16 f2bf(float f) {
  unsigned u = __builtin_bit_cast(unsigned, f);
  u += 0x7fffu + ((u >> 16) & 1u);
  return (u16)(u >> 16);
}
static __device__ __forceinline__ float bf2f(u16 h) {
  unsigned u = ((unsigned)h) << 16;
  return __builtin_bit_cast(float, u);
}

static __device__ __forceinline__ void load_lds16(const void* g, void* l) {
  __builtin_amdgcn_global_load_lds((const __attribute__((address_space(1))) void*)g,
                                   (__attribute__((address_space(3))) void*)l, 16, 0, 0);
}

#define BAR() __builtin_amdgcn_s_barrier()
#define VM(N) asm volatile("s_waitcnt vmcnt(" #N ")" ::: "memory")

// ---------------- merged f32 -> bf16 conversion (x4 vectorized) ----------------
__global__ void cvt_all_kernel(const float* __restrict__ x, const float* __restrict__ wq,
                               const float* __restrict__ wk, const float* __restrict__ wv,
                               const float* __restrict__ wo, u16* __restrict__ out) {
  const int i = blockIdx.x * 256 + threadIdx.x;  // float4 index, total 1835008
  const float* s;
  int base;
  if (i < 786432)       { s = x;  base = 0; }
  else if (i < 1048576) { s = wq; base = 786432; }
  else if (i < 1310720) { s = wk; base = 1048576; }
  else if (i < 1572864) { s = wv; base = 1310720; }
  else                  { s = wo; base = 1572864; }
  float4 v = reinterpret_cast<const float4*>(s)[i - base];
  unsigned long long o = (unsigned long long)f2bf(v.x) |
                         ((unsigned long long)f2bf(v.y) << 16) |
                         ((unsigned long long)f2bf(v.z) << 32) |
                         ((unsigned long long)f2bf(v.w) << 48);
  reinterpret_cast<unsigned long long*>(out)[i] = o;
}

// ================= QKV GEMM: 128x128 tile, 512 threads (8 waves), BK=32 =========
// LDS row = 32 shorts (64B); physical chunk = logical ^ ((row>>1)&3), both sides.
static __device__ __forceinline__ void stage_qkv(
    const u16* __restrict__ A, const u16* __restrict__ Bw,
    u16* As, u16* Bs, int rowBase, int colBase, int k0) {
  const int tid = threadIdx.x;
  const int w = tid >> 6;
  const int row = tid >> 2;
  const int j = (tid & 3) ^ ((row >> 1) & 3);
  load_lds16(A + (size_t)(rowBase + row) * HID + k0 + j * 8, As + (w * 64) * 8);
  load_lds16(Bw + (size_t)(colBase + row) * HID + k0 + j * 8, Bs + (w * 64) * 8);
}

// wave w: rows wr=(w>>2)*64 (4 m-frags); cols cb0=(c2>>1)*64+(c2&1)*16 and cb0+32
static __device__ __forceinline__ void compute_qkv(
    const u16* As, const u16* Bs, int wr, int cb0, int lc, int lh, f32x4 (*acc)[2]) {
  short8 af[4], bfv[2];
#pragma unroll
  for (int m = 0; m < 4; ++m) {
    const int row = wr + m * 16 + lc;
    af[m] = *reinterpret_cast<const short8*>(As + row * 32 + (lh ^ ((row >> 1) & 3)) * 8);
  }
#pragma unroll
  for (int n = 0; n < 2; ++n) {
    const int row = cb0 + n * 32 + lc;
    bfv[n] = *reinterpret_cast<const short8*>(Bs + row * 32 + (lh ^ ((row >> 1) & 3)) * 8);
  }
  __builtin_amdgcn_s_setprio(1);
#pragma unroll
  for (int m = 0; m < 4; ++m)
#pragma unroll
    for (int n = 0; n < 2; ++n)
      acc[m][n] = __builtin_amdgcn_mfma_f32_16x16x32_bf16(af[m], bfv[n], acc[m][n], 0, 0, 0);
  __builtin_amdgcn_s_setprio(0);
}

// grid: 576 (1-D). XCD-chunked: XCD g owns y in [3g, 3g+3) x all 24 x-tiles ->
// its 3 B-panels (768 KB) stay L2-resident; x streams once per XCD.
__global__ __launch_bounds__(512) void qkv_gemm_kernel(
    const u16* __restrict__ xb,
    const u16* __restrict__ wqb, const u16* __restrict__ wkb, const u16* __restrict__ wvb,
    const float* __restrict__ bq, const float* __restrict__ bk, const float* __restrict__ bv,
    u16* __restrict__ qb, u16* __restrict__ kbuf, u16* __restrict__ vT) {
  __shared__ u16 As[3][128 * 32];
  __shared__ u16 Bs[3][128 * 32];
  const int wgid = ((blockIdx.x & 7) * 72) + (blockIdx.x >> 3);
  const int by = wgid / 24;   // 0..23: (which<<3) | colTile
  const int bx = wgid % 24;   // row tile
  const int which = by >> 3;
  const u16* Bw = (which == 0) ? wqb : (which == 1) ? wkb : wvb;
  const float* bias = (which == 0) ? bq : (which == 1) ? bk : bv;
  const int rowBase = bx * 128;
  const int colBase = (by & 7) * 128;
  const int tid = threadIdx.x;
  const int w = tid >> 6, l = tid & 63, lc = l & 15, lh = l >> 4;
  const int wr = (w >> 2) * 64;
  const int c2 = w & 3;
  const int cb0 = (c2 >> 1) * 64 + (c2 & 1) * 16;

  f32x4 acc[4][2];
  f32x4 z4 = {0.f, 0.f, 0.f, 0.f};
#pragma unroll
  for (int m = 0; m < 4; ++m) { acc[m][0] = z4; acc[m][1] = z4; }

  stage_qkv(xb, Bw, As[0], Bs[0], rowBase, colBase, 0);
  stage_qkv(xb, Bw, As[1], Bs[1], rowBase, colBase, 32);
#pragma unroll 1
  for (int t = 0; t < 30; t += 3) {
    stage_qkv(xb, Bw, As[2], Bs[2], rowBase, colBase, (t + 2) * 32);
    VM(4); BAR();
    compute_qkv(As[0], Bs[0], wr, cb0, lc, lh, acc);
    BAR();
    stage_qkv(xb, Bw, As[0], Bs[0], rowBase, colBase, (t + 3) * 32);
    VM(4); BAR();
    compute_qkv(As[1], Bs[1], wr, cb0, lc, lh, acc);
    BAR();
    stage_qkv(xb, Bw, As[1], Bs[1], rowBase, colBase, (t + 4) * 32);
    VM(4); BAR();
    compute_qkv(As[2], Bs[2], wr, cb0, lc, lh, acc);
    BAR();
  }
  VM(2); BAR();
  compute_qkv(As[0], Bs[0], wr, cb0, lc, lh, acc);  // tile 30
  BAR();
  VM(0); BAR();
  compute_qkv(As[1], Bs[1], wr, cb0, lc, lh, acc);  // tile 31

  // epilogue: thread holds cols (col0, col0+32) -> RoPE pair is local
  const int f = (c2 & 1) * 16 + lc;  // [0,32)
  const int col0 = colBase + (c2 >> 1) * 64 + f;
  if (which < 2) {
    u16* outp = which ? kbuf : qb;
    const float bv0 = bias[col0];
    const float bv1 = bias[col0 + 32];
    const float invf = exp2f(-(float)f * 0.10381025296523007f);  // 10^(-f/32)
#pragma unroll
    for (int m = 0; m < 4; ++m) {
      const int row0 = rowBase + wr + m * 16 + lh * 4;
#pragma unroll
      for (int r = 0; r < 4; ++r) {
        const int row = row0 + r;
        const int rr = row % SEGSTR;
        const float pos = (float)((rr < SEGLEN) ? rr : 0);
        float sn, cs;
        sincosf(pos * invf, &sn, &cs);
        const float t1 = acc[m][0][r] + bv0;
        const float t2 = acc[m][1][r] + bv1;
        const size_t base = (size_t)row * HID + col0;
        outp[base] = f2bf(t1 * cs - t2 * sn);
        outp[base + 32] = f2bf(t1 * sn + t2 * cs);
      }
    }
  } else {
#pragma unroll
    for (int n = 0; n < 2; ++n) {
      const int col = col0 + n * 32;
      const float bvl = bias[col];
#pragma unroll
      for (int m = 0; m < 4; ++m) {
        const int row0 = rowBase + wr + m * 16 + lh * 4;
#pragma unroll
        for (int r = 0; r < 4; ++r) {
          const float v = acc[m][n][r] + bvl;
          const int row = row0 + r;
          const int sg = row / SEGSTR;
          const int j = row - sg * SEGSTR;
          if (sg < NSEG)
            vT[(size_t)col * (NSEG * VPAD) + sg * VPAD + j] = f2bf(v);
        }
      }
    }
  }
}

// ================= OUT GEMM: 128x64 tile, 512 threads (8 waves), BK=64 =========
// LDS row = 64 shorts (128B); physical chunk = logical ^ (row&7), both sides.
static __device__ __forceinline__ void stage_out(
    const u16* __restrict__ A, const u16* __restrict__ Bw,
    u16* As, u16* Bs, int rowBase, int colBase, int k0) {
  const int tid = threadIdx.x;
  const int w = tid >> 6;
#pragma unroll
  for (int c = 0; c < 2; ++c) {
    const int li = c * 512 + tid;
    const int row = li >> 3;
    const int j = (li & 7) ^ (row & 7);
    load_lds16(A + (size_t)(rowBase + row) * HID + k0 + j * 8,
               As + (c * 512 + w * 64) * 8);
  }
  {
    const int row = tid >> 3;
    const int j = (tid & 7) ^ (row & 7);
    load_lds16(Bw + (size_t)(colBase + row) * HID + k0 + j * 8, Bs + (w * 64) * 8);
  }
}

// wave w: rows wrO=(w>>1)*32 (2 m-frags), cols wcO=(w&1)*32 (2 n-frags), 2 k-subs
static __device__ __forceinline__ void compute_out(
    const u16* As, const u16* Bs, int wrO, int wcO, int lc, int lh, f32x4 (*acc)[2]) {
  short8 af[2][2], bfv[2][2];
#pragma unroll
  for (int m = 0; m < 2; ++m) {
    const int row = wrO + m * 16 + lc;
#pragma unroll
    for (int ks = 0; ks < 2; ++ks)
      af[m][ks] = *reinterpret_cast<const short8*>(
          As + row * 64 + (((ks * 4 + lh) ^ (row & 7))) * 8);
  }
#pragma unroll
  for (int n = 0; n < 2; ++n) {
    const int row = wcO + n * 16 + lc;
#pragma unroll
    for (int ks = 0; ks < 2; ++ks)
      bfv[n][ks] = *reinterpret_cast<const short8*>(
          Bs + row * 64 + (((ks * 4 + lh) ^ (row & 7))) * 8);
  }
  __builtin_amdgcn_s_setprio(1);
#pragma unroll
  for (int ks = 0; ks < 2; ++ks)
#pragma unroll
    for (int m = 0; m < 2; ++m)
#pragma unroll
      for (int n = 0; n < 2; ++n)
        acc[m][n] = __builtin_amdgcn_mfma_f32_16x16x32_bf16(af[m][ks], bfv[n][ks], acc[m][n], 0, 0, 0);
  __builtin_amdgcn_s_setprio(0);
}

// grid: 384 (1-D). XCD-chunked: XCD g owns col-panels [2g, 2g+2) x all 24 rows.
__global__ __launch_bounds__(512) void out_gemm_kernel(
    const u16* __restrict__ aob, const u16* __restrict__ wob,
    const float* __restrict__ bo, float* __restrict__ out) {
  __shared__ u16 As[3][128 * 64];
  __shared__ u16 Bs[3][64 * 64];
  const int wgid = ((blockIdx.x & 7) * 48) + (blockIdx.x >> 3);
  const int by = wgid / 24;   // 0..15
  const int bx = wgid % 24;
  const int rowBase = bx * 128;
  const int colBase = by * 64;
  const int tid = threadIdx.x;
  const int w = tid >> 6, l = tid & 63, lc = l & 15, lh = l >> 4;
  const int wrO = (w >> 1) * 32, wcO = (w & 1) * 32;
  f32x4 acc[2][2];
  f32x4 z4 = {0.f, 0.f, 0.f, 0.f};
#pragma unroll
  for (int m = 0; m < 2; ++m) { acc[m][0] = z4; acc[m][1] = z4; }

  stage_out(aob, wob, As[0], Bs[0], rowBase, colBase, 0);
  stage_out(aob, wob, As[1], Bs[1], rowBase, colBase, 64);
#pragma unroll 1
  for (int t = 0; t < 12; t += 3) {
    stage_out(aob, wob, As[2], Bs[2], rowBase, colBase, (t + 2) * 64);
    VM(6); BAR();
    compute_out(As[0], Bs[0], wrO, wcO, lc, lh, acc);
    BAR();
    stage_out(aob, wob, As[0], Bs[0], rowBase, colBase, (t + 3) * 64);
    VM(6); BAR();
    compute_out(As[1], Bs[1], wrO, wcO, lc, lh, acc);
    BAR();
    stage_out(aob, wob, As[1], Bs[1], rowBase, colBase, (t + 4) * 64);
    VM(6); BAR();
    compute_out(As[2], Bs[2], wrO, wcO, lc, lh, acc);
    BAR();
  }
  // computed 0..11, staged 0..13
  stage_out(aob, wob, As[2], Bs[2], rowBase, colBase, 14 * 64);
  VM(6); BAR();
  compute_out(As[0], Bs[0], wrO, wcO, lc, lh, acc);  // 12
  BAR();
  stage_out(aob, wob, As[0], Bs[0], rowBase, colBase, 15 * 64);
  VM(6); BAR();
  compute_out(As[1], Bs[1], wrO, wcO, lc, lh, acc);  // 13
  BAR();
  VM(3); BAR();
  compute_out(As[2], Bs[2], wrO, wcO, lc, lh, acc);  // 14
  BAR();
  VM(0); BAR();
  compute_out(As[0], Bs[0], wrO, wcO, lc, lh, acc);  // 15

#pragma unroll
  for (int n = 0; n < 2; ++n) {
    const int col = colBase + wcO + n * 16 + lc;
    const float bvl = bo[col];
#pragma unroll
    for (int m = 0; m < 2; ++m) {
      const int row0 = rowBase + wrO + m * 16 + lh * 4;
#pragma unroll
      for (int r = 0; r < 4; ++r)
        out[(size_t)(row0 + r) * HID + col] = acc[m][n][r] + bvl;
    }
  }
}

// ---------- block-diagonal flash attention (LDS-staged K/V, no-max softmax) -------
// Block = (qtile, seg, head) via XCD-chunked 1-D swizzle; 4 waves x 16 q-rows.
// K/V staged to LDS once per block (global_load_lds), triple-buffered, depth-2
// counted vmcnt. Fixup (separator/pad rows) fused into qt==5 blocks.
__global__ __launch_bounds__(256) void attn_kernel(
    const u16* __restrict__ qb, const u16* __restrict__ kb,
    const u16* __restrict__ vT, u16* __restrict__ ao) {
  __shared__ u16 Ks[3][32 * 64];
  __shared__ u16 Vs[3][64 * 32];
  __shared__ u16 P_lds[4][16 * 32];
  const int tid = threadIdx.x;
  const int w = tid >> 6, l = tid & 63, lc = l & 15, lh = l >> 4;
  // XCD-chunked swizzle: 768 blocks = 8 XCDs x 96; the 6 qtiles of a (seg,h)
  // group stay on one XCD -> K/V L2 reuse.
  const int W = (blockIdx.x & 7) * 96 + (blockIdx.x >> 3);
  const int qt = W % 6;
  const int seg = (W / 6) & 7;
  const int h = W / 48;
  const int segbase = seg * SEGSTR;
  const int rloc = qt * 64 + w * 16;

  const u16* qrow = qb + (size_t)(segbase + rloc + lc) * HID + h * HDIM + lh * 8;
  const short8 qf0 = *reinterpret_cast<const short8*>(qrow);
  const short8 qf1 = *reinterpret_cast<const short8*>(qrow + 32);

  const size_t vstride = (size_t)NSEG * VPAD;
  const u16* kseg = kb + (size_t)segbase * HID + h * HDIM;
  const u16* vseg = vT + (size_t)h * HDIM * vstride + seg * VPAD;

  // staging lane roles
  const int krow = tid >> 3;                       // 32 k-rows, 8 chunks of 16B
  const int kj = (tid & 7) ^ (krow & 7);           // pre-swizzled source chunk
  const int vd = tid >> 2;                         // 64 d-rows, 4 chunks of 16B
  const int vj = (tid & 3) ^ ((vd >> 2) & 3);

  f32x4 z4 = {0.f, 0.f, 0.f, 0.f};
  f32x4 accO[4] = {z4, z4, z4, z4};
  float psum[4] = {0.f, 0.f, 0.f, 0.f};

  // P_lds (per-wave [16 q][32 k]) swizzled offsets
  u16* pl = &P_lds[w][0];
  int wo0[4], wo1[4];
#pragma unroll
  for (int r = 0; r < 4; ++r) {
    const int prow = lh * 4 + r;
    const int sw = (prow >> 1) & 3;
    wo0[r] = prow * 32 + ((lc >> 3) ^ sw) * 8 + (lc & 7);
    wo1[r] = prow * 32 + ((2 + (lc >> 3)) ^ sw) * 8 + (lc & 7);
  }
  const int prd_off = lc * 32 + (lh ^ ((lc >> 1) & 3)) * 8;

#define STAGE(B, T)                                                                 \
  load_lds16(kseg + (size_t)((T) * 32 + krow) * HID + kj * 8, &Ks[B][0] + w * 512); \
  load_lds16(vseg + (size_t)vd * vstride + (T) * 32 + vj * 8, &Vs[B][0] + w * 512);

#define STEP(B, MASKED)                                                               \
  {                                                                                   \
    const u16* KB = &Ks[B][0];                                                        \
    const u16* VB = &Vs[B][0];                                                        \
    const int ks0 = (lh ^ (lc & 7)) * 8;                                              \
    const int ks1 = ((lh + 4) ^ (lc & 7)) * 8;                                        \
    const short8 k00 = *reinterpret_cast<const short8*>(KB + lc * 64 + ks0);          \
    const short8 k01 = *reinterpret_cast<const short8*>(KB + lc * 64 + ks1);          \
    const short8 k10 = *reinterpret_cast<const short8*>(KB + (16 + lc) * 64 + ks0);   \
    const short8 k11 = *reinterpret_cast<const short8*>(KB + (16 + lc) * 64 + ks1);   \
    f32x4 s0 = z4, s1 = z4;                                                           \
    __builtin_amdgcn_s_setprio(1);                                                    \
    s0 = __builtin_amdgcn_mfma_f32_16x16x32_bf16(qf0, k00, s0, 0, 0, 0);              \
    s0 = __builtin_amdgcn_mfma_f32_16x16x32_bf16(qf1, k01, s0, 0, 0, 0);              \
    s1 = __builtin_amdgcn_mfma_f32_16x16x32_bf16(qf0, k10, s1, 0, 0, 0);              \
    s1 = __builtin_amdgcn_mfma_f32_16x16x32_bf16(qf1, k11, s1, 0, 0, 0);              \
    __builtin_amdgcn_s_setprio(0);                                                    \
    float p0[4], p1[4];                                                               \
    _Pragma("unroll") for (int r = 0; r < 4; ++r) {                                   \
      p0[r] = (!(MASKED) || lc < 28) ? __expf(s0[r] * 0.125f) : 0.f;                  \
      p1[r] = (!(MASKED) || lc < 12) ? __expf(s1[r] * 0.125f) : 0.f;                  \
      psum[r] += p0[r] + p1[r];                                                       \
    }                                                                                 \
    _Pragma("unroll") for (int r = 0; r < 4; ++r) {                                   \
      pl[wo0[r]] = f2bf(p0[r]);                                                       \
      pl[wo1[r]] = f2bf(p1[r]);                                                       \
    }                                                                                 \
    const short8 pf = *reinterpret_cast<const short8*>(pl + prd_off);                 \
    const int vsw = (lh ^ (lc >> 2)) * 8;                                             \
    const short8 v0 = *reinterpret_cast<const short8*>(VB + lc * 32 + vsw);           \
    const short8 v1 = *reinterpret_cast<const short8*>(VB + (16 + lc) * 32 + vsw);    \
    const short8 v2 = *reinterpret_cast<const short8*>(VB + (32 + lc) * 32 + vsw);    \
    const short8 v3 = *reinterpret_cast<const short8*>(VB + (48 + lc) * 32 + vsw);    \
    __builtin_amdgcn_s_setprio(1);                                                    \
    accO[0] = __builtin_amdgcn_mfma_f32_16x16x32_bf16(pf, v0, accO[0], 0, 0, 0);      \
    accO[1] = __builtin_amdgcn_mfma_f32_16x16x32_bf16(pf, v1, accO[1], 0, 0, 0);      \
    accO[2] = __builtin_amdgcn_mfma_f32_16x16x32_bf16(pf, v2, accO[2], 0, 0, 0);      \
    accO[3] = __builtin_amdgcn_mfma_f32_16x16x32_bf16(pf, v3, accO[3], 0, 0, 0);      \
    __builtin_amdgcn_s_setprio(0);                                                    \
  }

  STAGE(0, 0);
  STAGE(1, 1);
#pragma unroll 1
  for (int t = 0; t < 9; t += 3) {
    STAGE(2, t + 2);
    VM(4); BAR();
    STEP(0, false);
    BAR();
    STAGE(0, t + 3);
    VM(4); BAR();
    STEP(1, false);
    BAR();
    STAGE(1, t + 4);
    VM(4); BAR();
    STEP(2, false);
    BAR();
  }
  // steps 0..8 done; staged 9(b0), 10(b1). Step 9 + stage 11(b2):
  STAGE(2, 11);
  VM(4); BAR();
  STEP(0, false);  // step 9
  BAR();
  VM(2); BAR();
  STEP(1, false);  // step 10
  BAR();
  VM(0); BAR();
  STEP(2, true);   // step 11: k rows 352..383, mask k >= 380
#undef STEP
#undef STAGE

  float inv[4];
#pragma unroll
  for (int r = 0; r < 4; ++r) {
    float s = psum[r];
    s += __shfl_xor(s, 1);
    s += __shfl_xor(s, 2);
    s += __shfl_xor(s, 4);
    s += __shfl_xor(s, 8);
    inv[r] = 1.0f / s;
  }
#pragma unroll
  for (int r = 0; r < 4; ++r) {
    const int lrow = rloc + lh * 4 + r;
    if (lrow < SEGLEN) {
      const size_t orow = (size_t)(segbase + lrow) * HID + h * HDIM;
#pragma unroll
      for (int n = 0; n < 4; ++n)
        ao[orow + n * 16 + lc] = f2bf(accO[n][r] * inv[r]);
    }
  }

  // fused fixup: qt==5 blocks also write separator / pad rows for (seg, h)
  if (qt == 5) {
    if (seg < NSEG - 1) {
      if (tid < HDIM)
        ao[(size_t)(segbase + SEGLEN) * HID + h * HDIM + tid] =
            vT[(size_t)(h * HDIM + tid) * vstride + seg * VPAD + SEGLEN];
    } else {
      // zero rows 3047..3071 in this head's 64 columns (25 rows x 64 cols)
#pragma unroll
      for (int k = 0; k < 7; ++k) {
        const int idx = k * 256 + tid;
        if (idx < 25 * HDIM) {
          const int rr = idx >> 6, cc = idx & 63;
          ao[(size_t)(LTOT + rr) * HID + h * HDIM + cc] = 0;
        }
      }
    }
  }
}

extern "C" void kernel_launch(void* const* d_in, const int* in_sizes, int n_in,
                              void* d_out, int out_size, void* d_ws, size_t ws_size,
                              hipStream_t stream) {
  const float* x  = (const float*)d_in[0];
  const float* wq = (const float*)d_in[1];
  const float* bq = (const float*)d_in[2];
  const float* wk = (const float*)d_in[3];
  const float* bk = (const float*)d_in[4];
  const float* wv = (const float*)d_in[5];
  const float* bv = (const float*)d_in[6];
  const float* wo = (const float*)d_in[7];
  const float* bo = (const float*)d_in[8];
  float* out = (float*)d_out;

  u16* ws = (u16*)d_ws;
  u16* xb   = ws;                    // SEQ*HID
  u16* wqb  = xb  + (size_t)SEQ * HID;
  u16* wkb  = wqb + (size_t)HID * HID;
  u16* wvb  = wkb + (size_t)HID * HID;
  u16* wob  = wvb + (size_t)HID * HID;
  u16* qb   = wob + (size_t)HID * HID;
  u16* kbuf = qb  + (size_t)SEQ * HID;
  u16* vT   = kbuf + (size_t)SEQ * HID;  // [HID][NSEG*VPAD]
  u16* aob  = vT  + (size_t)HID * (NSEG * VPAD);

  cvt_all_kernel<<<7168, 256, 0, stream>>>(x, wq, wk, wv, wo, ws);

  qkv_gemm_kernel<<<576, 512, 0, stream>>>(
      xb, wqb, wkb, wvb, bq, bk, bv, qb, kbuf, vT);

  attn_kernel<<<768, 256, 0, stream>>>(qb, kbuf, vT, aob);

  out_gemm_kernel<<<384, 512, 0, stream>>>(aob, wob, bo, out);

  (void)in_sizes; (void)n_in; (void)out_size; (void)ws_size;
}

// Round 11
// 79.690 us; speedup vs baseline: 1.1220x; 1.1220x over previous
//
#include <hip/hip_runtime.h>

typedef unsigned short u16;
typedef __attribute__((ext_vector_type(8))) short short8;
typedef __attribute__((ext_vector_type(4))) float f32x4;

#define SEQ 3072
#define HID 1024
#define HEADS 16
#define HDIM 64
#define SEGLEN 380
#define SEGSTR 381
#define NSEG 8
#define LTOT 3047
#define VPAD 384  // padded per-segment stride in vT (16B-aligned bases)

static __device__ __forceinline__ u16 f2bf(float f) {
  unsigned u = __builtin_bit_cast(unsigned, f);
  u += 0x7fffu + ((u >> 16) & 1u);
  return (u16)(u >> 16);
}
static __device__ __forceinline__ float bf2f(u16 h) {
  unsigned u = ((unsigned)h) << 16;
  return __builtin_bit_cast(float, u);
}

static __device__ __forceinline__ void load_lds16(const void* g, void* l) {
  __builtin_amdgcn_global_load_lds((const __attribute__((address_space(1))) void*)g,
                                   (__attribute__((address_space(3))) void*)l, 16, 0, 0);
}

#define BAR() __builtin_amdgcn_s_barrier()
#define VM(N) asm volatile("s_waitcnt vmcnt(" #N ")" ::: "memory")

// ---------------- merged f32 -> bf16 conversion (x4 vectorized) ----------------
__global__ void cvt_all_kernel(const float* __restrict__ x, const float* __restrict__ wq,
                               const float* __restrict__ wk, const float* __restrict__ wv,
                               const float* __restrict__ wo, u16* __restrict__ out) {
  const int i = blockIdx.x * 256 + threadIdx.x;  // float4 index, total 1835008
  const float* s;
  int base;
  if (i < 786432)       { s = x;  base = 0; }
  else if (i < 1048576) { s = wq; base = 786432; }
  else if (i < 1310720) { s = wk; base = 1048576; }
  else if (i < 1572864) { s = wv; base = 1310720; }
  else                  { s = wo; base = 1572864; }
  float4 v = reinterpret_cast<const float4*>(s)[i - base];
  unsigned long long o = (unsigned long long)f2bf(v.x) |
                         ((unsigned long long)f2bf(v.y) << 16) |
                         ((unsigned long long)f2bf(v.z) << 32) |
                         ((unsigned long long)f2bf(v.w) << 48);
  reinterpret_cast<unsigned long long*>(out)[i] = o;
}

// ================= QKV GEMM: 128x128 tile, 512 threads (8 waves), BK=32 =========
// LDS row = 32 shorts (64B); physical chunk = logical ^ ((row>>1)&3), both sides.
static __device__ __forceinline__ void stage_qkv(
    const u16* __restrict__ A, const u16* __restrict__ Bw,
    u16* As, u16* Bs, int rowBase, int colBase, int k0) {
  const int tid = threadIdx.x;
  const int w = tid >> 6;
  const int row = tid >> 2;
  const int j = (tid & 3) ^ ((row >> 1) & 3);
  load_lds16(A + (size_t)(rowBase + row) * HID + k0 + j * 8, As + (w * 64) * 8);
  load_lds16(Bw + (size_t)(colBase + row) * HID + k0 + j * 8, Bs + (w * 64) * 8);
}

// wave w: rows wr=(w>>2)*64 (4 m-frags); cols cb0=(c2>>1)*64+(c2&1)*16 and cb0+32
static __device__ __forceinline__ void compute_qkv(
    const u16* As, const u16* Bs, int wr, int cb0, int lc, int lh, f32x4 (*acc)[2]) {
  short8 af[4], bfv[2];
#pragma unroll
  for (int m = 0; m < 4; ++m) {
    const int row = wr + m * 16 + lc;
    af[m] = *reinterpret_cast<const short8*>(As + row * 32 + (lh ^ ((row >> 1) & 3)) * 8);
  }
#pragma unroll
  for (int n = 0; n < 2; ++n) {
    const int row = cb0 + n * 32 + lc;
    bfv[n] = *reinterpret_cast<const short8*>(Bs + row * 32 + (lh ^ ((row >> 1) & 3)) * 8);
  }
  __builtin_amdgcn_s_setprio(1);
#pragma unroll
  for (int m = 0; m < 4; ++m)
#pragma unroll
    for (int n = 0; n < 2; ++n)
      acc[m][n] = __builtin_amdgcn_mfma_f32_16x16x32_bf16(af[m], bfv[n], acc[m][n], 0, 0, 0);
  __builtin_amdgcn_s_setprio(0);
}

// grid: (SEQ/128, 24); blockIdx.y: /8 -> {q,k,v}, &7 -> 128-col tile
__global__ __launch_bounds__(512) void qkv_gemm_kernel(
    const u16* __restrict__ xb,
    const u16* __restrict__ wqb, const u16* __restrict__ wkb, const u16* __restrict__ wvb,
    const float* __restrict__ bq, const float* __restrict__ bk, const float* __restrict__ bv,
    u16* __restrict__ qb, u16* __restrict__ kbuf, u16* __restrict__ vT) {
  __shared__ u16 As[3][128 * 32];
  __shared__ u16 Bs[3][128 * 32];
  const int which = blockIdx.y >> 3;
  const u16* Bw = (which == 0) ? wqb : (which == 1) ? wkb : wvb;
  const float* bias = (which == 0) ? bq : (which == 1) ? bk : bv;
  const int rowBase = blockIdx.x * 128;
  const int colBase = (blockIdx.y & 7) * 128;
  const int tid = threadIdx.x;
  const int w = tid >> 6, l = tid & 63, lc = l & 15, lh = l >> 4;
  const int wr = (w >> 2) * 64;
  const int c2 = w & 3;
  const int cb0 = (c2 >> 1) * 64 + (c2 & 1) * 16;

  f32x4 acc[4][2];
  f32x4 z4 = {0.f, 0.f, 0.f, 0.f};
#pragma unroll
  for (int m = 0; m < 4; ++m) { acc[m][0] = z4; acc[m][1] = z4; }

  stage_qkv(xb, Bw, As[0], Bs[0], rowBase, colBase, 0);
  stage_qkv(xb, Bw, As[1], Bs[1], rowBase, colBase, 32);
#pragma unroll 1
  for (int t = 0; t < 30; t += 3) {
    stage_qkv(xb, Bw, As[2], Bs[2], rowBase, colBase, (t + 2) * 32);
    VM(4); BAR();
    compute_qkv(As[0], Bs[0], wr, cb0, lc, lh, acc);
    BAR();
    stage_qkv(xb, Bw, As[0], Bs[0], rowBase, colBase, (t + 3) * 32);
    VM(4); BAR();
    compute_qkv(As[1], Bs[1], wr, cb0, lc, lh, acc);
    BAR();
    stage_qkv(xb, Bw, As[1], Bs[1], rowBase, colBase, (t + 4) * 32);
    VM(4); BAR();
    compute_qkv(As[2], Bs[2], wr, cb0, lc, lh, acc);
    BAR();
  }
  VM(2); BAR();
  compute_qkv(As[0], Bs[0], wr, cb0, lc, lh, acc);  // tile 30
  BAR();
  VM(0); BAR();
  compute_qkv(As[1], Bs[1], wr, cb0, lc, lh, acc);  // tile 31

  // epilogue: thread holds cols (col0, col0+32) -> RoPE pair is local
  const int f = (c2 & 1) * 16 + lc;  // [0,32)
  const int col0 = colBase + (c2 >> 1) * 64 + f;
  if (which < 2) {
    u16* outp = which ? kbuf : qb;
    const float bv0 = bias[col0];
    const float bv1 = bias[col0 + 32];
    const float invf = exp2f(-(float)f * 0.10381025296523007f);  // 10^(-f/32)
#pragma unroll
    for (int m = 0; m < 4; ++m) {
      const int row0 = rowBase + wr + m * 16 + lh * 4;
#pragma unroll
      for (int r = 0; r < 4; ++r) {
        const int row = row0 + r;
        const int rr = row % SEGSTR;
        const float pos = (float)((rr < SEGLEN) ? rr : 0);
        float sn, cs;
        sincosf(pos * invf, &sn, &cs);
        const float t1 = acc[m][0][r] + bv0;
        const float t2 = acc[m][1][r] + bv1;
        const size_t base = (size_t)row * HID + col0;
        outp[base] = f2bf(t1 * cs - t2 * sn);
        outp[base + 32] = f2bf(t1 * sn + t2 * cs);
      }
    }
  } else {
#pragma unroll
    for (int n = 0; n < 2; ++n) {
      const int col = col0 + n * 32;
      const float bvl = bias[col];
#pragma unroll
      for (int m = 0; m < 4; ++m) {
        const int row0 = rowBase + wr + m * 16 + lh * 4;
#pragma unroll
        for (int r = 0; r < 4; ++r) {
          const float v = acc[m][n][r] + bvl;
          const int row = row0 + r;
          const int sg = row / SEGSTR;
          const int j = row - sg * SEGSTR;
          if (sg < NSEG)
            vT[(size_t)col * (NSEG * VPAD) + sg * VPAD + j] = f2bf(v);
        }
      }
    }
  }
}

// ================= OUT GEMM: 128x64 tile, 512 threads (8 waves), BK=64 =========
// LDS row = 64 shorts (128B); physical chunk = logical ^ (row&7), both sides.
static __device__ __forceinline__ void stage_out(
    const u16* __restrict__ A, const u16* __restrict__ Bw,
    u16* As, u16* Bs, int rowBase, int colBase, int k0) {
  const int tid = threadIdx.x;
  const int w = tid >> 6;
#pragma unroll
  for (int c = 0; c < 2; ++c) {
    const int li = c * 512 + tid;
    const int row = li >> 3;
    const int j = (li & 7) ^ (row & 7);
    load_lds16(A + (size_t)(rowBase + row) * HID + k0 + j * 8,
               As + (c * 512 + w * 64) * 8);
  }
  {
    const int row = tid >> 3;
    const int j = (tid & 7) ^ (row & 7);
    load_lds16(Bw + (size_t)(colBase + row) * HID + k0 + j * 8, Bs + (w * 64) * 8);
  }
}

// wave w: rows wrO=(w>>1)*32 (2 m-frags), cols wcO=(w&1)*32 (2 n-frags), 2 k-subs
static __device__ __forceinline__ void compute_out(
    const u16* As, const u16* Bs, int wrO, int wcO, int lc, int lh, f32x4 (*acc)[2]) {
  short8 af[2][2], bfv[2][2];
#pragma unroll
  for (int m = 0; m < 2; ++m) {
    const int row = wrO + m * 16 + lc;
#pragma unroll
    for (int ks = 0; ks < 2; ++ks)
      af[m][ks] = *reinterpret_cast<const short8*>(
          As + row * 64 + (((ks * 4 + lh) ^ (row & 7))) * 8);
  }
#pragma unroll
  for (int n = 0; n < 2; ++n) {
    const int row = wcO + n * 16 + lc;
#pragma unroll
    for (int ks = 0; ks < 2; ++ks)
      bfv[n][ks] = *reinterpret_cast<const short8*>(
          Bs + row * 64 + (((ks * 4 + lh) ^ (row & 7))) * 8);
  }
  __builtin_amdgcn_s_setprio(1);
#pragma unroll
  for (int ks = 0; ks < 2; ++ks)
#pragma unroll
    for (int m = 0; m < 2; ++m)
#pragma unroll
      for (int n = 0; n < 2; ++n)
        acc[m][n] = __builtin_amdgcn_mfma_f32_16x16x32_bf16(af[m][ks], bfv[n][ks], acc[m][n], 0, 0, 0);
  __builtin_amdgcn_s_setprio(0);
}

// grid: (SEQ/128, HID/64), 512 threads
__global__ __launch_bounds__(512) void out_gemm_kernel(
    const u16* __restrict__ aob, const u16* __restrict__ wob,
    const float* __restrict__ bo, float* __restrict__ out) {
  __shared__ u16 As[3][128 * 64];
  __shared__ u16 Bs[3][64 * 64];
  const int rowBase = blockIdx.x * 128;
  const int colBase = blockIdx.y * 64;
  const int tid = threadIdx.x;
  const int w = tid >> 6, l = tid & 63, lc = l & 15, lh = l >> 4;
  const int wrO = (w >> 1) * 32, wcO = (w & 1) * 32;
  f32x4 acc[2][2];
  f32x4 z4 = {0.f, 0.f, 0.f, 0.f};
#pragma unroll
  for (int m = 0; m < 2; ++m) { acc[m][0] = z4; acc[m][1] = z4; }

  stage_out(aob, wob, As[0], Bs[0], rowBase, colBase, 0);
  stage_out(aob, wob, As[1], Bs[1], rowBase, colBase, 64);
#pragma unroll 1
  for (int t = 0; t < 12; t += 3) {
    stage_out(aob, wob, As[2], Bs[2], rowBase, colBase, (t + 2) * 64);
    VM(6); BAR();
    compute_out(As[0], Bs[0], wrO, wcO, lc, lh, acc);
    BAR();
    stage_out(aob, wob, As[0], Bs[0], rowBase, colBase, (t + 3) * 64);
    VM(6); BAR();
    compute_out(As[1], Bs[1], wrO, wcO, lc, lh, acc);
    BAR();
    stage_out(aob, wob, As[1], Bs[1], rowBase, colBase, (t + 4) * 64);
    VM(6); BAR();
    compute_out(As[2], Bs[2], wrO, wcO, lc, lh, acc);
    BAR();
  }
  // computed 0..11, staged 0..13
  stage_out(aob, wob, As[2], Bs[2], rowBase, colBase, 14 * 64);
  VM(6); BAR();
  compute_out(As[0], Bs[0], wrO, wcO, lc, lh, acc);  // 12
  BAR();
  stage_out(aob, wob, As[0], Bs[0], rowBase, colBase, 15 * 64);
  VM(6); BAR();
  compute_out(As[1], Bs[1], wrO, wcO, lc, lh, acc);  // 13
  BAR();
  VM(3); BAR();
  compute_out(As[2], Bs[2], wrO, wcO, lc, lh, acc);  // 14
  BAR();
  VM(0); BAR();
  compute_out(As[0], Bs[0], wrO, wcO, lc, lh, acc);  // 15

#pragma unroll
  for (int n = 0; n < 2; ++n) {
    const int col = colBase + wcO + n * 16 + lc;
    const float bvl = bo[col];
#pragma unroll
    for (int m = 0; m < 2; ++m) {
      const int row0 = rowBase + wrO + m * 16 + lh * 4;
#pragma unroll
      for (int r = 0; r < 4; ++r)
        out[(size_t)(row0 + r) * HID + col] = acc[m][n][r] + bvl;
    }
  }
}

// ---------- block-diagonal flash attention (LDS-staged K/V, no-max softmax) -------
// Block = (qtile, seg, head) via XCD-chunked 1-D swizzle; 4 waves x 16 q-rows.
// K/V staged to LDS once per block (global_load_lds), triple-buffered, depth-2
// counted vmcnt. Fixup (separator/pad rows) fused into qt==5 blocks.
__global__ __launch_bounds__(256) void attn_kernel(
    const u16* __restrict__ qb, const u16* __restrict__ kb,
    const u16* __restrict__ vT, u16* __restrict__ ao) {
  __shared__ u16 Ks[3][32 * 64];
  __shared__ u16 Vs[3][64 * 32];
  __shared__ u16 P_lds[4][16 * 32];
  const int tid = threadIdx.x;
  const int w = tid >> 6, l = tid & 63, lc = l & 15, lh = l >> 4;
  // XCD-chunked swizzle: 768 blocks = 8 XCDs x 96; the 6 qtiles of a (seg,h)
  // group stay on one XCD -> K/V L2 reuse.
  const int W = (blockIdx.x & 7) * 96 + (blockIdx.x >> 3);
  const int qt = W % 6;
  const int seg = (W / 6) & 7;
  const int h = W / 48;
  const int segbase = seg * SEGSTR;
  const int rloc = qt * 64 + w * 16;

  const u16* qrow = qb + (size_t)(segbase + rloc + lc) * HID + h * HDIM + lh * 8;
  const short8 qf0 = *reinterpret_cast<const short8*>(qrow);
  const short8 qf1 = *reinterpret_cast<const short8*>(qrow + 32);

  const size_t vstride = (size_t)NSEG * VPAD;
  const u16* kseg = kb + (size_t)segbase * HID + h * HDIM;
  const u16* vseg = vT + (size_t)h * HDIM * vstride + seg * VPAD;

  // staging lane roles
  const int krow = tid >> 3;                       // 32 k-rows, 8 chunks of 16B
  const int kj = (tid & 7) ^ (krow & 7);           // pre-swizzled source chunk
  const int vd = tid >> 2;                         // 64 d-rows, 4 chunks of 16B
  const int vj = (tid & 3) ^ ((vd >> 2) & 3);

  f32x4 z4 = {0.f, 0.f, 0.f, 0.f};
  f32x4 accO[4] = {z4, z4, z4, z4};
  float psum[4] = {0.f, 0.f, 0.f, 0.f};

  // P_lds (per-wave [16 q][32 k]) swizzled offsets
  u16* pl = &P_lds[w][0];
  int wo0[4], wo1[4];
#pragma unroll
  for (int r = 0; r < 4; ++r) {
    const int prow = lh * 4 + r;
    const int sw = (prow >> 1) & 3;
    wo0[r] = prow * 32 + ((lc >> 3) ^ sw) * 8 + (lc & 7);
    wo1[r] = prow * 32 + ((2 + (lc >> 3)) ^ sw) * 8 + (lc & 7);
  }
  const int prd_off = lc * 32 + (lh ^ ((lc >> 1) & 3)) * 8;

#define STAGE(B, T)                                                                 \
  load_lds16(kseg + (size_t)((T) * 32 + krow) * HID + kj * 8, &Ks[B][0] + w * 512); \
  load_lds16(vseg + (size_t)vd * vstride + (T) * 32 + vj * 8, &Vs[B][0] + w * 512);

#define STEP(B, MASKED)                                                               \
  {                                                                                   \
    const u16* KB = &Ks[B][0];                                                        \
    const u16* VB = &Vs[B][0];                                                        \
    const int ks0 = (lh ^ (lc & 7)) * 8;                                              \
    const int ks1 = ((lh + 4) ^ (lc & 7)) * 8;                                        \
    const short8 k00 = *reinterpret_cast<const short8*>(KB + lc * 64 + ks0);          \
    const short8 k01 = *reinterpret_cast<const short8*>(KB + lc * 64 + ks1);          \
    const short8 k10 = *reinterpret_cast<const short8*>(KB + (16 + lc) * 64 + ks0);   \
    const short8 k11 = *reinterpret_cast<const short8*>(KB + (16 + lc) * 64 + ks1);   \
    f32x4 s0 = z4, s1 = z4;                                                           \
    __builtin_amdgcn_s_setprio(1);                                                    \
    s0 = __builtin_amdgcn_mfma_f32_16x16x32_bf16(qf0, k00, s0, 0, 0, 0);              \
    s0 = __builtin_amdgcn_mfma_f32_16x16x32_bf16(qf1, k01, s0, 0, 0, 0);              \
    s1 = __builtin_amdgcn_mfma_f32_16x16x32_bf16(qf0, k10, s1, 0, 0, 0);              \
    s1 = __builtin_amdgcn_mfma_f32_16x16x32_bf16(qf1, k11, s1, 0, 0, 0);              \
    __builtin_amdgcn_s_setprio(0);                                                    \
    float p0[4], p1[4];                                                               \
    _Pragma("unroll") for (int r = 0; r < 4; ++r) {                                   \
      p0[r] = (!(MASKED) || lc < 28) ? __expf(s0[r] * 0.125f) : 0.f;                  \
      p1[r] = (!(MASKED) || lc < 12) ? __expf(s1[r] * 0.125f) : 0.f;                  \
      psum[r] += p0[r] + p1[r];                                                       \
    }                                                                                 \
    _Pragma("unroll") for (int r = 0; r < 4; ++r) {                                   \
      pl[wo0[r]] = f2bf(p0[r]);                                                       \
      pl[wo1[r]] = f2bf(p1[r]);                                                       \
    }                                                                                 \
    const short8 pf = *reinterpret_cast<const short8*>(pl + prd_off);                 \
    const int vsw = (lh ^ (lc >> 2)) * 8;                                             \
    const short8 v0 = *reinterpret_cast<const short8*>(VB + lc * 32 + vsw);           \
    const short8 v1 = *reinterpret_cast<const short8*>(VB + (16 + lc) * 32 + vsw);    \
    const short8 v2 = *reinterpret_cast<const short8*>(VB + (32 + lc) * 32 + vsw);    \
    const short8 v3 = *reinterpret_cast<const short8*>(VB + (48 + lc) * 32 + vsw);    \
    __builtin_amdgcn_s_setprio(1);                                                    \
    accO[0] = __builtin_amdgcn_mfma_f32_16x16x32_bf16(pf, v0, accO[0], 0, 0, 0);      \
    accO[1] = __builtin_amdgcn_mfma_f32_16x16x32_bf16(pf, v1, accO[1], 0, 0, 0);      \
    accO[2] = __builtin_amdgcn_mfma_f32_16x16x32_bf16(pf, v2, accO[2], 0, 0, 0);      \
    accO[3] = __builtin_amdgcn_mfma_f32_16x16x32_bf16(pf, v3, accO[3], 0, 0, 0);      \
    __builtin_amdgcn_s_setprio(0);                                                    \
  }

  STAGE(0, 0);
  STAGE(1, 1);
#pragma unroll 1
  for (int t = 0; t < 9; t += 3) {
    STAGE(2, t + 2);
    VM(4); BAR();
    STEP(0, false);
    BAR();
    STAGE(0, t + 3);
    VM(4); BAR();
    STEP(1, false);
    BAR();
    STAGE(1, t + 4);
    VM(4); BAR();
    STEP(2, false);
    BAR();
  }
  // steps 0..8 done; staged 9(b0), 10(b1). Step 9 + stage 11(b2):
  STAGE(2, 11);
  VM(4); BAR();
  STEP(0, false);  // step 9
  BAR();
  VM(2); BAR();
  STEP(1, false);  // step 10
  BAR();
  VM(0); BAR();
  STEP(2, true);   // step 11: k rows 352..383, mask k >= 380
#undef STEP
#undef STAGE

  float inv[4];
#pragma unroll
  for (int r = 0; r < 4; ++r) {
    float s = psum[r];
    s += __shfl_xor(s, 1);
    s += __shfl_xor(s, 2);
    s += __shfl_xor(s, 4);
    s += __shfl_xor(s, 8);
    inv[r] = 1.0f / s;
  }
#pragma unroll
  for (int r = 0; r < 4; ++r) {
    const int lrow = rloc + lh * 4 + r;
    if (lrow < SEGLEN) {
      const size_t orow = (size_t)(segbase + lrow) * HID + h * HDIM;
#pragma unroll
      for (int n = 0; n < 4; ++n)
        ao[orow + n * 16 + lc] = f2bf(accO[n][r] * inv[r]);
    }
  }

  // fused fixup: qt==5 blocks also write separator / pad rows for (seg, h)
  if (qt == 5) {
    if (seg < NSEG - 1) {
      if (tid < HDIM)
        ao[(size_t)(segbase + SEGLEN) * HID + h * HDIM + tid] =
            vT[(size_t)(h * HDIM + tid) * vstride + seg * VPAD + SEGLEN];
    } else {
      // zero rows 3047..3071 in this head's 64 columns (25 rows x 64 cols)
#pragma unroll
      for (int k = 0; k < 7; ++k) {
        const int idx = k * 256 + tid;
        if (idx < 25 * HDIM) {
          const int rr = idx >> 6, cc = idx & 63;
          ao[(size_t)(LTOT + rr) * HID + h * HDIM + cc] = 0;
        }
      }
    }
  }
}

extern "C" void kernel_launch(void* const* d_in, const int* in_sizes, int n_in,
                              void* d_out, int out_size, void* d_ws, size_t ws_size,
                              hipStream_t stream) {
  const float* x  = (const float*)d_in[0];
  const float* wq = (const float*)d_in[1];
  const float* bq = (const float*)d_in[2];
  const float* wk = (const float*)d_in[3];
  const float* bk = (const float*)d_in[4];
  const float* wv = (const float*)d_in[5];
  const float* bv = (const float*)d_in[6];
  const float* wo = (const float*)d_in[7];
  const float* bo = (const float*)d_in[8];
  float* out = (float*)d_out;

  u16* ws = (u16*)d_ws;
  u16* xb   = ws;                    // SEQ*HID
  u16* wqb  = xb  + (size_t)SEQ * HID;
  u16* wkb  = wqb + (size_t)HID * HID;
  u16* wvb  = wkb + (size_t)HID * HID;
  u16* wob  = wvb + (size_t)HID * HID;
  u16* qb   = wob + (size_t)HID * HID;
  u16* kbuf = qb  + (size_t)SEQ * HID;
  u16* vT   = kbuf + (size_t)SEQ * HID;  // [HID][NSEG*VPAD]
  u16* aob  = vT  + (size_t)HID * (NSEG * VPAD);

  cvt_all_kernel<<<7168, 256, 0, stream>>>(x, wq, wk, wv, wo, ws);

  qkv_gemm_kernel<<<dim3(SEQ / 128, 24), 512, 0, stream>>>(
      xb, wqb, wkb, wvb, bq, bk, bv, qb, kbuf, vT);

  attn_kernel<<<768, 256, 0, stream>>>(qb, kbuf, vT, aob);

  out_gemm_kernel<<<dim3(SEQ / 128, HID / 64), 512, 0, stream>>>(aob, wob, bo, out);

  (void)in_sizes; (void)n_in; (void)out_size; (void)ws_size;
}